// Round 1
// baseline (234.037 us; speedup 1.0000x reference)
//
#include <hip/hip_runtime.h>

#define BATCH 8192
#define MDIM 128
#define NL 10
#define LSTEPS 97
#define RSTEPS 96
#define NSTEPS 193   // LSTEPS + RSTEPS
#define DIM 196
#define POSL 98

typedef _Float16 half8 __attribute__((ext_vector_type(8)));
typedef float float16v __attribute__((ext_vector_type(16)));

// lgkm-only barrier: orders LDS ops; never drains vmcnt (register prefetches fly).
#define BARRIER_LGKM() asm volatile("s_waitcnt lgkmcnt(0)\ns_barrier" ::: "memory")

#define MFMA16 __builtin_amdgcn_mfma_f32_32x32x16_f16

// ---------------------------------------------------------------------------
// Transpose x into xT[pos][batch] (float2). Kills the 1568B-stride scatter in
// the chain kernel's per-step x prefetch (32 lines -> 1-2 lines per load).
// Tile: 64 batch x 32 pos, via two float planes in LDS (stride 65: 2-way max).
// ---------------------------------------------------------------------------
__global__ __launch_bounds__(256) void transpose_x(const float* __restrict__ x,
                                                   float2* __restrict__ xT) {
    __shared__ float tx[64][65];
    __shared__ float ty[64][65];
    int p0 = blockIdx.x * 32;
    int b0 = blockIdx.y * 64;
    int tid = threadIdx.x;

    // read: thread r = tid>>2 (batch row), q = tid&3 -> pos chunk q*8..q*8+7
    int r = tid >> 2, q = tid & 3;
    const float* src = x + ((size_t)(b0 + r) * DIM + p0 + q * 8) * 2;
#pragma unroll
    for (int j = 0; j < 8; ++j) {
        int pp = q * 8 + j;
        if (p0 + pp < DIM) {
            float2 v = *(const float2*)(src + j * 2);
            tx[r][pp] = v.x;
            ty[r][pp] = v.y;
        }
    }
    __syncthreads();

    // write: thread pr = tid>>3 (pos 0..31), cq = tid&7 -> batch chunk cq*8
    int pr = tid >> 3, cb = (tid & 7) * 8;
    if (p0 + pr < DIM) {
        float2* dst = xT + (size_t)(p0 + pr) * BATCH + b0 + cb;
#pragma unroll
        for (int j = 0; j < 8; ++j) {
            float2 v;
            v.x = tx[cb + j][pr];
            v.y = ty[cb + j][pr];
            dst[j] = v;
        }
    }
}

// ---------------------------------------------------------------------------
// Pack chain weights into f16 A-fragment order for v_mfma_f32_32x32x16_f16:
// pw[(g*64 + nt*16 + kt)*512 + l*8 + j] = W_g[k=kt*16+(l>>5)*8+j][n=nt*32+(l&31)]
// left (g<97): W_g[k=s*128+m][n] = w_left[g][s][m][n]
// right(g>=97): t=g-97, W_g[k=s*128+a][n] = w_right[95-t][s][n][a]
// ---------------------------------------------------------------------------
__global__ __launch_bounds__(256) void pack_w(const float* __restrict__ w_left,
                                              const float* __restrict__ w_right,
                                              _Float16* __restrict__ pw) {
    int g = blockIdx.x >> 2;
    int nt = blockIdx.x & 3;
    int tid = threadIdx.x;
    int l = tid & 63;
    int kq = tid >> 6;
    int hi = l >> 5;
    int n = nt * 32 + (l & 31);
#pragma unroll
    for (int p = 0; p < 4; ++p) {
        int kt = p * 4 + kq;
        int k0 = kt * 16 + hi * 8;
        half8 hv;
        if (g < LSTEPS) {
            const float* base = w_left + (size_t)g * 2 * MDIM * MDIM;
#pragma unroll
            for (int j = 0; j < 8; ++j)
                hv[j] = (_Float16)base[(size_t)(k0 + j) * MDIM + n];
        } else {
            int t = g - LSTEPS;
            int s = k0 >> 7;
            int a0 = k0 & 127;
            const float* row = w_right + (size_t)(RSTEPS - 1 - t) * 2 * MDIM * MDIM
                             + (size_t)s * MDIM * MDIM + (size_t)n * MDIM + a0;
#pragma unroll
            for (int j = 0; j < 8; ++j) hv[j] = (_Float16)row[j];
        }
        *(half8*)(pw + (size_t)(g * 64 + nt * 16 + kt) * 512 + l * 8) = hv;
    }
}

// ---------------------------------------------------------------------------
// Pack w_label into f16 A-frag order with l-major columns (unchanged).
// ---------------------------------------------------------------------------
__global__ __launch_bounds__(256) void pack_label(const float* __restrict__ w_label,
                                                  _Float16* __restrict__ gp) {
    int ct = blockIdx.x;               // 0..39
    int tid = threadIdx.x;
    int l = tid & 63;
    int kq = tid >> 6;
    int hi = l >> 5;
    int outcol = ct * 32 + (l & 31);
    int n = outcol & 127;
    int lab = outcol >> 7;
#pragma unroll
    for (int p2 = 0; p2 < 4; ++p2) {
        int kt = p2 * 4 + kq;
        int k0 = kt * 16 + hi * 8;
        int p = k0 >> 7;
        int m0 = k0 & 127;
        half8 hv;
#pragma unroll
        for (int j = 0; j < 8; ++j)
            hv[j] = (_Float16)w_label[(((size_t)p * MDIM + m0 + j) * MDIM + n) * NL + lab];
        *(half8*)(gp + (size_t)(ct * 16 + kt) * 512 + l * 8) = hv;
    }
}

// ---------------------------------------------------------------------------
// Chain kernel v8: 256 blocks x 256 threads (4 waves = 4 n-tiles), TB=64.
// Changes vs v7:
//  - x prefetch from xT[pos][batch]: coalesced (was 32 scattered lines/load).
//  - row-group stagger: rg0 accumulator chains finish 2 k-tiles early; rg1's
//    tail MFMAs are issued before the rg0 epilogue so the epilogue VALU runs
//    under in-flight MFMAs (separate pipes).
// ---------------------------------------------------------------------------

// MFMA block: 4-chain interleave for kt<6 (latency-safe), then rg0 finishes,
// then rg1 tail issues last so the following rg0 epilogue overlaps it.
#define CHAIN_MFMA_BLOCK(AF, SRC)                                            \
    half8 bf0[8], bf1[8];                                                    \
    _Pragma("unroll")                                                        \
    for (int q = 0; q < 8; ++q) {                                            \
        int nb = q * 2 + hi;                                                 \
        int phys = nb ^ (bl & 15);                                           \
        bf0[q] = *(const half8*)&cbuf[SRC][bl * 128 + phys * 8];             \
        bf1[q] = *(const half8*)&cbuf[SRC][(bl + 32) * 128 + phys * 8];      \
    }                                                                        \
    float16v a00 = {}, a01 = {}, a10 = {}, a11 = {};                         \
    _Pragma("unroll")                                                        \
    for (int kt = 0; kt < 6; ++kt) {                                         \
        a00 = MFMA16(AF[kt], bf0[kt], a00, 0, 0, 0);                         \
        a10 = MFMA16(AF[kt], bf1[kt], a10, 0, 0, 0);                         \
        a01 = MFMA16(AF[kt + 8], bf0[kt], a01, 0, 0, 0);                     \
        a11 = MFMA16(AF[kt + 8], bf1[kt], a11, 0, 0, 0);                     \
    }                                                                        \
    a00 = MFMA16(AF[6], bf0[6], a00, 0, 0, 0);                               \
    a01 = MFMA16(AF[14], bf0[6], a01, 0, 0, 0);                              \
    a00 = MFMA16(AF[7], bf0[7], a00, 0, 0, 0);                               \
    a01 = MFMA16(AF[15], bf0[7], a01, 0, 0, 0);                              \
    a10 = MFMA16(AF[6], bf1[6], a10, 0, 0, 0);                               \
    a11 = MFMA16(AF[14], bf1[6], a11, 0, 0, 0);                              \
    a10 = MFMA16(AF[7], bf1[7], a10, 0, 0, 0);                               \
    a11 = MFMA16(AF[15], bf1[7], a11, 0, 0, 0);

#define EPI_RG(DST, XC, A_LO, A_HI, ROWOFF)                                  \
    _Pragma("unroll")                                                        \
    for (int rq = 0; rq < 4; ++rq) {                                         \
        int nb = nt * 4 + rq;                                                \
        int phys = nb ^ (bl & 15);                                           \
        union { _Float16 h[4]; uint2 u; } t;                                 \
        _Pragma("unroll")                                                    \
        for (int r = 0; r < 4; ++r)                                          \
            t.h[r] = (_Float16)((XC).x * A_LO[rq * 4 + r]                    \
                              + (XC).y * A_HI[rq * 4 + r]);                  \
        *(uint2*)&cbuf[DST][(bl + ROWOFF) * 128 + phys * 8 + hi * 4] = t.u;  \
    }

#define FINAL_STORE()                                                        \
    _Pragma("unroll")                                                        \
    for (int r = 0; r < 16; ++r) {                                           \
        int n = nt * 32 + (r & 3) + 8 * (r >> 2) + 4 * hi;                   \
        outT[(size_t)n * BATCH + bbase + bl] = xc0.x * a00[r] + xc0.y * a01[r]; \
        outT[(size_t)n * BATCH + bbase + 32 + bl] = xc1.x * a10[r] + xc1.y * a11[r]; \
    }

__global__ __launch_bounds__(256, 1) void chain_mfma(
        const float2* __restrict__ xT, const float* __restrict__ w0,
        const float* __restrict__ w_end, const _Float16* __restrict__ pw,
        float* __restrict__ leftT, float* __restrict__ rightT) {
    __shared__ _Float16 cbuf[2][64 * 128];   // 2 x 16 KB carry

    int bid = blockIdx.x;
    bool is_left = bid < 128;
    int bbase = (is_left ? bid : bid - 128) * 64;
    int tid = threadIdx.x;
    int l = tid & 63;
    int nt = tid >> 6;        // wave = n-tile
    int bl = l & 31;
    int hi = l >> 5;

    int nsteps = is_left ? LSTEPS : RSTEPS;
    int gbase = is_left ? 0 : LSTEPS;
    float* outT = is_left ? leftT : rightT;

    // --- initial carry into cbuf[0] (256 threads cover 64 rows x 128 cols)
    {
        const float* wst = is_left ? w0 : w_end;
        int pos0 = is_left ? 0 : (DIM - 1);
        int b = tid >> 2;                        // 0..63
        const float2 xv0 = xT[(size_t)pos0 * BATCH + bbase + b];
#pragma unroll
        for (int h = 0; h < 4; ++h) {
            int nb = (tid & 3) * 4 + h;          // 0..15
            half8 hv;
#pragma unroll
            for (int j = 0; j < 8; ++j) {
                int n = nb * 8 + j;
                hv[j] = (_Float16)(xv0.x * wst[n] + xv0.y * wst[MDIM + n]);
            }
            int phys = nb ^ (b & 15);
            *(half8*)&cbuf[0][b * 128 + phys * 8] = hv;
        }
    }

    // per-wave A base: frag kt at pwb + step*65536 + kt*1024 (bytes)
    const char* pwb = (const char*)pw + (size_t)(gbase * 64 + nt * 16) * 1024
                    + (size_t)l * 16;
    const float2* xTb = xT + bbase;

    half8 A0[16], A1[16];
#pragma unroll
    for (int kt = 0; kt < 16; ++kt)
        A0[kt] = *(const half8*)(pwb + kt * 1024);
    int p00 = is_left ? 1 : (DIM - 2);
    float2 xc0 = xTb[(size_t)p00 * BATCH + bl];
    float2 xc1 = xTb[(size_t)p00 * BATCH + 32 + bl];

    __syncthreads();   // carry init visible

    int npairs = nsteps >> 1;          // 48 for both chains
    bool odd = nsteps & 1;             // left: 1, right: 0
    int last = nsteps - 1;

#pragma unroll 1
    for (int sp = 0; sp < npairs; ++sp) {
        int s0 = 2 * sp;
        // ---------- even step s0: consume A0, prefetch A1 <- step s0+1 ----------
        {
            // x first (older than A prefetch -> its waits never drain A)
            int pnext = is_left ? (2 + s0) : (DIM - 3 - s0);
            float2 xn0 = xTb[(size_t)pnext * BATCH + bl];
            float2 xn1 = xTb[(size_t)pnext * BATCH + 32 + bl];
            const char* pn = pwb + (size_t)(s0 + 1) * 65536;
#pragma unroll
            for (int kt = 0; kt < 16; ++kt)
                A1[kt] = *(const half8*)(pn + kt * 1024);

            CHAIN_MFMA_BLOCK(A0, 0)
            // epilogue (even step is never the final step); rg0 epilogue
            // overlaps rg1's tail MFMAs issued just above.
            EPI_RG(1, xc0, a00, a01, 0)
            EPI_RG(1, xc1, a10, a11, 32)
            BARRIER_LGKM();
            xc0 = xn0; xc1 = xn1;
        }
        // ---------- odd step s1 = s0+1: consume A1, prefetch A0 <- s0+2 ----------
        {
            int s1 = s0 + 1;
            int pf = (s0 + 2 <= last) ? (s0 + 2) : last;   // clamp (harmless reload)
            int ppf = is_left ? (1 + pf) : (DIM - 2 - pf);
            float2 xn0 = xTb[(size_t)ppf * BATCH + bl];
            float2 xn1 = xTb[(size_t)ppf * BATCH + 32 + bl];
            const char* pn = pwb + (size_t)pf * 65536;
#pragma unroll
            for (int kt = 0; kt < 16; ++kt)
                A0[kt] = *(const half8*)(pn + kt * 1024);

            CHAIN_MFMA_BLOCK(A1, 1)
            if (s1 == last) {
                // final step (right chain): store fp32 transposed [n][BATCH]
                FINAL_STORE()
            } else {
                EPI_RG(0, xc0, a00, a01, 0)
                EPI_RG(0, xc1, a10, a11, 32)
                BARRIER_LGKM();
            }
            xc0 = xn0; xc1 = xn1;
        }
    }

    if (odd) {   // tail step = nsteps-1 (left chain), consume A0
        CHAIN_MFMA_BLOCK(A0, 0)
        FINAL_STORE()
    }
}

// ---------------------------------------------------------------------------
// Label contraction via MFMA (xl read moved to xT; otherwise unchanged).
// ---------------------------------------------------------------------------
__global__ __launch_bounds__(256, 2) void label_mfma(
        const float2* __restrict__ xT, const _Float16* __restrict__ gp,
        const float* __restrict__ leftT, const float* __restrict__ rightT,
        float* __restrict__ out) {
    __shared__ _Float16 R[32 * 256];     // 16 KB
    __shared__ float pl[4][32][5];
    __shared__ float xl_s[32][2];

    int bx = blockIdx.x;                 // 0/1 -> labels [bx*5, +5)
    int bbase = blockIdx.y * 32;
    int tid = threadIdx.x;
    int l = tid & 63, nt = tid >> 6, bl = l & 31, hi = l >> 5;

    if (tid < 32) {
        const float2 v = xT[(size_t)POSL * BATCH + bbase + tid];
        xl_s[tid][0] = v.x; xl_s[tid][1] = v.y;
    }
    __syncthreads();

#pragma unroll
    for (int q = 0; q < 4; ++q) {
        int id = tid + q * 256;          // 0..1023
        int m = id >> 3;
        int b4 = (id & 7) * 4;
        float4 v = *(const float4*)&leftT[(size_t)m * BATCH + bbase + b4];
        float vv[4] = {v.x, v.y, v.z, v.w};
#pragma unroll
        for (int bi = 0; bi < 4; ++bi) {
            int b = b4 + bi;
            int kb0 = m >> 3;
            int ph0 = (kb0 & 16) | ((kb0 ^ b) & 15);
            R[b * 256 + ph0 * 8 + (m & 7)] = (_Float16)(xl_s[b][0] * vv[bi]);
            int kb1 = kb0 + 16;
            int ph1 = (kb1 & 16) | ((kb1 ^ b) & 15);
            R[b * 256 + ph1 * 8 + (m & 7)] = (_Float16)(xl_s[b][1] * vv[bi]);
        }
    }

    float rv[16];
#pragma unroll
    for (int r = 0; r < 16; ++r) {
        int n = nt * 32 + (r & 3) + 8 * (r >> 2) + 4 * hi;
        rv[r] = rightT[(size_t)n * BATCH + bbase + bl];
    }
    __syncthreads();

    half8 rf[16];
#pragma unroll
    for (int kt = 0; kt < 16; ++kt) {
        int kb = kt * 2 + hi;
        int ph = (kb & 16) | ((kb ^ bl) & 15);
        rf[kt] = *(const half8*)&R[bl * 256 + ph * 8];
    }

    int l0 = bx * 5;
    float outv[5];
#pragma unroll
    for (int li = 0; li < 5; ++li) {
        int ct = (l0 + li) * 4 + nt;
        float16v acc = {};
#pragma unroll
        for (int kt = 0; kt < 16; ++kt) {
            half8 a = *(const half8*)(gp + (size_t)(ct * 16 + kt) * 512 + l * 8);
            acc = __builtin_amdgcn_mfma_f32_32x32x16_f16(a, rf[kt], acc, 0, 0, 0);
        }
        float p = 0.f;
#pragma unroll
        for (int r = 0; r < 16; ++r) p += acc[r] * rv[r];
        p += __shfl_xor(p, 32, 64);
        outv[li] = p;
    }
    if (hi == 0) {
#pragma unroll
        for (int li = 0; li < 5; ++li) pl[nt][bl][li] = outv[li];
    }
    __syncthreads();
    if (tid < 160) {
        int b = tid / 5, li = tid % 5;
        out[(size_t)(bbase + b) * NL + l0 + li] =
            pl[0][b][li] + pl[1][b][li] + pl[2][b][li] + pl[3][b][li];
    }
}

// ---------------------------------------------------------------------------
extern "C" void kernel_launch(void* const* d_in, const int* in_sizes, int n_in,
                              void* d_out, int out_size, void* d_ws, size_t ws_size,
                              hipStream_t stream) {
    const float* x       = (const float*)d_in[0];
    const float* w0      = (const float*)d_in[1];
    const float* w_left  = (const float*)d_in[2];
    const float* w_label = (const float*)d_in[3];
    const float* w_right = (const float*)d_in[4];
    const float* w_end   = (const float*)d_in[5];

    _Float16* pw = (_Float16*)d_ws;                               // 12.65 MB
    _Float16* gp = pw + (size_t)NSTEPS * 64 * 512;                // 0.66 MB
    float* leftT  = (float*)(gp + (size_t)40 * 16 * 512);         // 4 MB
    float* rightT = leftT + (size_t)MDIM * BATCH;                 // 4 MB
    float2* xT    = (float2*)(rightT + (size_t)MDIM * BATCH);     // 12.85 MB

    transpose_x<<<dim3((DIM + 31) / 32, BATCH / 64), 256, 0, stream>>>(x, xT);
    pack_w<<<dim3(NSTEPS * 4), 256, 0, stream>>>(w_left, w_right, pw);
    pack_label<<<dim3(40), 256, 0, stream>>>(w_label, gp);
    chain_mfma<<<dim3(256), 256, 0, stream>>>(xT, w0, w_end, pw, leftT, rightT);
    label_mfma<<<dim3(2, BATCH / 32), 256, 0, stream>>>(xT, gp, leftT, rightT,
                                                        (float*)d_out);
}